// Round 1
// baseline (222.605 us; speedup 1.0000x reference)
//
#include <hip/hip_runtime.h>

typedef __attribute__((ext_vector_type(8))) short bf16x8;
typedef __attribute__((ext_vector_type(4))) float f32x4;

#define MFMA16(A, Bv, C) __builtin_amdgcn_mfma_f32_16x16x32_bf16((A), (Bv), (C), 0, 0, 0)

static constexpr int NB = 4, NS = 4096, ND = 1024, NH = 64;

__device__ __forceinline__ unsigned short f2bf(float f) {
    union { float f; unsigned int u; } x; x.f = f;
    unsigned int r = x.u + 0x7fffu + ((x.u >> 16) & 1u);
    return (unsigned short)(r >> 16);
}

// ---------------------------------------------------------------------------
// Kernel 1: fused QKV projection.  x[16384][1024] fp32  ->  q,k bf16 [16384][64]
// (q pre-scaled by 1/8), and vT bf16 [4][64][4096] (transposed for attention).
// Block: 256 threads (4 waves), M-tile = 64 rows, BK = 32.
// ---------------------------------------------------------------------------
__global__ __launch_bounds__(256) void qkv_proj(
    const float* __restrict__ x,  const float* __restrict__ Wq,
    const float* __restrict__ Wk, const float* __restrict__ Wv,
    unsigned short* __restrict__ qo, unsigned short* __restrict__ ko,
    unsigned short* __restrict__ vt)
{
    __shared__ unsigned short xs[64][40];        // x tile, bf16, padded (+8) vs bank conflicts
    __shared__ unsigned short ws[3][64][40];     // W^T tiles: ws[m][n][k]
    __shared__ unsigned short Ls[64][72];        // v transpose staging

    const int tid  = threadIdx.x;
    const int lane = tid & 63;
    const int w    = tid >> 6;
    const int lr   = lane & 15;
    const int lg   = lane >> 4;
    const int mbase = blockIdx.x * 64;

    const float* Wm[3] = {Wq, Wk, Wv};

    f32x4 acc[3][4];
    #pragma unroll
    for (int m = 0; m < 3; ++m)
        #pragma unroll
        for (int f = 0; f < 4; ++f)
            acc[m][f] = (f32x4){0.f, 0.f, 0.f, 0.f};

    for (int kt = 0; kt < ND / 32; ++kt) {
        // stage x tile 64x32 -> bf16 LDS
        {
            int row = tid >> 2;
            int c8  = (tid & 3) * 8;
            const float* src = x + (size_t)(mbase + row) * ND + kt * 32 + c8;
            float4 u0 = *(const float4*)src;
            float4 u1 = *(const float4*)(src + 4);
            unsigned short* dst = &xs[row][c8];
            dst[0] = f2bf(u0.x); dst[1] = f2bf(u0.y); dst[2] = f2bf(u0.z); dst[3] = f2bf(u0.w);
            dst[4] = f2bf(u1.x); dst[5] = f2bf(u1.y); dst[6] = f2bf(u1.z); dst[7] = f2bf(u1.w);
        }
        // stage W tiles 32x64 -> transposed bf16 LDS  ws[m][n][k]
        {
            int kk = tid >> 3;
            int n8 = (tid & 7) * 8;
            #pragma unroll
            for (int m = 0; m < 3; ++m) {
                const float* src = Wm[m] + (size_t)(kt * 32 + kk) * NH + n8;
                float4 u0 = *(const float4*)src;
                float4 u1 = *(const float4*)(src + 4);
                ws[m][n8 + 0][kk] = f2bf(u0.x); ws[m][n8 + 1][kk] = f2bf(u0.y);
                ws[m][n8 + 2][kk] = f2bf(u0.z); ws[m][n8 + 3][kk] = f2bf(u0.w);
                ws[m][n8 + 4][kk] = f2bf(u1.x); ws[m][n8 + 5][kk] = f2bf(u1.y);
                ws[m][n8 + 6][kk] = f2bf(u1.z); ws[m][n8 + 7][kk] = f2bf(u1.w);
            }
        }
        __syncthreads();

        bf16x8 a = *(const bf16x8*)&xs[w * 16 + lr][lg * 8];
        #pragma unroll
        for (int m = 0; m < 3; ++m)
            #pragma unroll
            for (int f = 0; f < 4; ++f) {
                bf16x8 bfr = *(const bf16x8*)&ws[m][f * 16 + lr][lg * 8];
                acc[m][f] = MFMA16(a, bfr, acc[m][f]);
            }
        __syncthreads();
    }

    // epilogue: q (scaled), k row-major; v -> LDS transpose -> vT[b][h][s]
    #pragma unroll
    for (int f = 0; f < 4; ++f)
        #pragma unroll
        for (int r = 0; r < 4; ++r) {
            int srow = w * 16 + lg * 4 + r;          // C/D layout: row=(lane>>4)*4+reg
            int col  = lr + 16 * f;                  //             col=lane&15
            size_t grow = (size_t)(mbase + srow);
            qo[grow * NH + col] = f2bf(acc[0][f][r] * 0.125f);
            ko[grow * NH + col] = f2bf(acc[1][f][r]);
            Ls[srow][col] = f2bf(acc[2][f][r]);
        }
    __syncthreads();
    {
        int h   = tid >> 2;          // 0..63
        int s16 = (tid & 3) * 16;    // 0,16,32,48
        unsigned short tmp[16];
        #pragma unroll
        for (int j = 0; j < 16; ++j) tmp[j] = Ls[s16 + j][h];
        int b  = mbase >> 12;
        int sb = mbase & (NS - 1);
        unsigned short* dst = vt + ((size_t)(b * NH + h)) * NS + sb + s16;
        bf16x8 v0, v1;
        #pragma unroll
        for (int j = 0; j < 8; ++j) { v0[j] = (short)tmp[j]; v1[j] = (short)tmp[8 + j]; }
        *(bf16x8*)dst       = v0;
        *(bf16x8*)(dst + 8) = v1;
    }
}

// ---------------------------------------------------------------------------
// Kernel 2: causal flash attention. One wave per block, 16 q-rows per wave,
// KV tiles of 64. K/V read straight from global (L2-resident); only P staged
// in LDS for the C-layout -> A-layout redistribution.
// ---------------------------------------------------------------------------
__global__ __launch_bounds__(64) void attn_fwd(
    const unsigned short* __restrict__ q, const unsigned short* __restrict__ k,
    const unsigned short* __restrict__ vt, float* __restrict__ out)
{
    __shared__ unsigned short Ps[16][72];

    const int lane = threadIdx.x;
    const int lr = lane & 15;
    const int lg = lane >> 4;

    // heavy-first: consecutive blockIdx cycle batches, descending q-tile
    const int b  = blockIdx.x & 3;
    const int qt = 255 - (int)(blockIdx.x >> 2);
    const int qb = qt * 16;
    const size_t bq = (size_t)b * NS;

    bf16x8 qf0, qf1;
    {
        const unsigned short* qp = q + (bq + qb + lr) * NH + lg * 8;
        qf0 = *(const bf16x8*)qp;
        qf1 = *(const bf16x8*)(qp + 32);
    }

    f32x4 O[4];
    #pragma unroll
    for (int i = 0; i < 4; ++i) O[i] = (f32x4){0.f, 0.f, 0.f, 0.f};
    float mrow[4], lsum[4];
    #pragma unroll
    for (int r = 0; r < 4; ++r) { mrow[r] = -3.0e38f; lsum[r] = 0.f; }

    const int nt = (qb >> 6) + 1;
    for (int t = 0; t < nt; ++t) {
        const int kvb = t * 64;

        // S = Q K^T  (A = Q[16q][64d], B = K^T read as contiguous rows of k)
        f32x4 sf[4];
        #pragma unroll
        for (int f = 0; f < 4; ++f) {
            f32x4 s = (f32x4){0.f, 0.f, 0.f, 0.f};
            const unsigned short* kp = k + (bq + kvb + lr + 16 * f) * NH + lg * 8;
            s = MFMA16(qf0, *(const bf16x8*)kp, s);
            s = MFMA16(qf1, *(const bf16x8*)(kp + 32), s);
            sf[f] = s;
        }

        // causal mask (only diagonal tile needs it)
        if (t == nt - 1) {
            #pragma unroll
            for (int f = 0; f < 4; ++f) {
                int kvg = kvb + lr + 16 * f;
                #pragma unroll
                for (int r = 0; r < 4; ++r) {
                    int qg = qb + lg * 4 + r;
                    if (kvg > qg) sf[f][r] = -3.0e38f;
                }
            }
        }

        // online softmax, row r lives in lanes {lg*16..lg*16+15} -> shfl_xor<16
        #pragma unroll
        for (int r = 0; r < 4; ++r) {
            float pm = fmaxf(fmaxf(sf[0][r], sf[1][r]), fmaxf(sf[2][r], sf[3][r]));
            #pragma unroll
            for (int m = 1; m < 16; m <<= 1) pm = fmaxf(pm, __shfl_xor(pm, m));
            float mnew = fmaxf(mrow[r], pm);
            float corr = __expf(mrow[r] - mnew);
            mrow[r] = mnew;
            float rs = 0.f;
            #pragma unroll
            for (int f = 0; f < 4; ++f) {
                float p = __expf(sf[f][r] - mnew);
                sf[f][r] = p;
                rs += p;
            }
            #pragma unroll
            for (int m = 1; m < 16; m <<= 1) rs += __shfl_xor(rs, m);
            lsum[r] = lsum[r] * corr + rs;
            #pragma unroll
            for (int hf = 0; hf < 4; ++hf) O[hf][r] *= corr;
        }

        // P: C-layout -> LDS -> A-layout
        #pragma unroll
        for (int f = 0; f < 4; ++f)
            #pragma unroll
            for (int r = 0; r < 4; ++r)
                Ps[lg * 4 + r][lr + 16 * f] = f2bf(sf[f][r]);

        bf16x8 pa0 = *(const bf16x8*)&Ps[lr][lg * 8];
        bf16x8 pa1 = *(const bf16x8*)&Ps[lr][lg * 8 + 32];

        // O += P V   (B-frags contiguous from vT[b][h][s])
        #pragma unroll
        for (int hf = 0; hf < 4; ++hf) {
            const unsigned short* vp = vt + ((size_t)(b * NH + lr + 16 * hf)) * NS + kvb + lg * 8;
            O[hf] = MFMA16(pa0, *(const bf16x8*)vp, O[hf]);
            O[hf] = MFMA16(pa1, *(const bf16x8*)(vp + 32), O[hf]);
        }
    }

    // epilogue: O / l, fp32 out[b][s][h]
    #pragma unroll
    for (int r = 0; r < 4; ++r) {
        float inv = 1.f / lsum[r];
        float* op = out + (bq + qb + lg * 4 + r) * NH + lr;
        #pragma unroll
        for (int hf = 0; hf < 4; ++hf) op[16 * hf] = O[hf][r] * inv;
    }
}

extern "C" void kernel_launch(void* const* d_in, const int* in_sizes, int n_in,
                              void* d_out, int out_size, void* d_ws, size_t ws_size,
                              hipStream_t stream)
{
    const float* x  = (const float*)d_in[0];
    const float* Wq = (const float*)d_in[1];
    const float* Wk = (const float*)d_in[2];
    const float* Wv = (const float*)d_in[3];
    float* out = (float*)d_out;

    const size_t n = (size_t)NB * NS * NH;          // 1M elements per tensor
    unsigned short* qb = (unsigned short*)d_ws;     // 2 MB
    unsigned short* kb = qb + n;                    // 2 MB
    unsigned short* vT = kb + n;                    // 2 MB (layout [b][h][s])

    qkv_proj<<<dim3((NB * NS) / 64), dim3(256), 0, stream>>>(x, Wq, Wk, Wv, qb, kb, vT);
    attn_fwd<<<dim3(NB * (NS / 16)), dim3(64), 0, stream>>>(qb, kb, vT, out);
}

// Round 2
// 132.645 us; speedup vs baseline: 1.6782x; 1.6782x over previous
//
#include <hip/hip_runtime.h>

typedef __attribute__((ext_vector_type(8))) short bf16x8;
typedef __attribute__((ext_vector_type(4))) float f32x4;

#define MFMA16(A, Bv, C) __builtin_amdgcn_mfma_f32_16x16x32_bf16((A), (Bv), (C), 0, 0, 0)

static constexpr int NB = 4, NS = 4096, ND = 1024, NH = 64;

__device__ __forceinline__ unsigned short f2bf(float f) {
    union { float f; unsigned int u; } x; x.f = f;
    unsigned int r = x.u + 0x7fffu + ((x.u >> 16) & 1u);
    return (unsigned short)(r >> 16);
}

// ---------------------------------------------------------------------------
// Kernel 0: W[D][H] fp32 -> wT[m][n][k] bf16  (3 x 64 x 1024, 384 KB, L2-hot)
// ---------------------------------------------------------------------------
__global__ __launch_bounds__(256) void wconv(
    const float* __restrict__ Wq, const float* __restrict__ Wk,
    const float* __restrict__ Wv, unsigned short* __restrict__ wT)
{
    int mn = blockIdx.x;                 // 0..191 = m*64 + n
    int m = mn >> 6, n = mn & 63;
    const float* W = (m == 0) ? Wq : (m == 1) ? Wk : Wv;
    unsigned short* dst = wT + (size_t)mn * ND;
    for (int k = threadIdx.x; k < ND; k += 256)
        dst[k] = f2bf(W[(size_t)k * NH + n]);
}

// ---------------------------------------------------------------------------
// Kernel 1: QKV projection, barrier-free K-loop.
// Block = 256 thr (4 waves) owns 16 rows; wave w owns K-quarter [w*256, w*256+256).
// A-frags straight from x (fp32->bf16 in reg), B-frags straight from wT (L2).
// One barrier + LDS reduce, wave 0 does the epilogue (q*0.125, k, v-transpose).
// ---------------------------------------------------------------------------
__global__ __launch_bounds__(256) void qkv_proj(
    const float* __restrict__ x, const unsigned short* __restrict__ wT,
    unsigned short* __restrict__ qo, unsigned short* __restrict__ ko,
    unsigned short* __restrict__ vt)
{
    __shared__ float red[3][64][48];          // waves 1..3 partial acc
    __shared__ unsigned short Ls[16][72];     // v transpose staging

    const int tid  = threadIdx.x;
    const int lane = tid & 63;
    const int w    = tid >> 6;
    const int lr   = lane & 15;
    const int lg   = lane >> 4;
    const int mbase = blockIdx.x * 16;

    f32x4 acc[3][4];
    #pragma unroll
    for (int m = 0; m < 3; ++m)
        #pragma unroll
        for (int f = 0; f < 4; ++f)
            acc[m][f] = (f32x4){0.f, 0.f, 0.f, 0.f};

    const int kw = w * 256;
    for (int it = 0; it < 8; ++it) {
        const int k0 = kw + it * 32 + lg * 8;
        const float* xp = x + (size_t)(mbase + lr) * ND + k0;
        float4 u0 = *(const float4*)xp;
        float4 u1 = *(const float4*)(xp + 4);
        bf16x8 a;
        a[0] = (short)f2bf(u0.x); a[1] = (short)f2bf(u0.y);
        a[2] = (short)f2bf(u0.z); a[3] = (short)f2bf(u0.w);
        a[4] = (short)f2bf(u1.x); a[5] = (short)f2bf(u1.y);
        a[6] = (short)f2bf(u1.z); a[7] = (short)f2bf(u1.w);
        #pragma unroll
        for (int m = 0; m < 3; ++m)
            #pragma unroll
            for (int f = 0; f < 4; ++f) {
                bf16x8 bfr = *(const bf16x8*)(wT + (size_t)(m * 64 + f * 16 + lr) * ND + k0);
                acc[m][f] = MFMA16(a, bfr, acc[m][f]);
            }
    }

    if (w) {
        #pragma unroll
        for (int m = 0; m < 3; ++m)
            #pragma unroll
            for (int f = 0; f < 4; ++f)
                #pragma unroll
                for (int r = 0; r < 4; ++r)
                    red[w - 1][lane][(m * 4 + f) * 4 + r] = acc[m][f][r];
    }
    __syncthreads();
    if (w == 0) {
        #pragma unroll
        for (int m = 0; m < 3; ++m)
            #pragma unroll
            for (int f = 0; f < 4; ++f)
                #pragma unroll
                for (int r = 0; r < 4; ++r) {
                    float s = acc[m][f][r];
                    s += red[0][lane][(m * 4 + f) * 4 + r];
                    s += red[1][lane][(m * 4 + f) * 4 + r];
                    s += red[2][lane][(m * 4 + f) * 4 + r];
                    acc[m][f][r] = s;
                }
        // epilogue: q (scaled), k row-major; v -> LDS -> transposed vT[b][h][s]
        #pragma unroll
        for (int f = 0; f < 4; ++f)
            #pragma unroll
            for (int r = 0; r < 4; ++r) {
                int srow = lg * 4 + r;               // C/D: row=(lane>>4)*4+reg
                int col  = lr + 16 * f;              //      col=lane&15
                size_t grow = (size_t)(mbase + srow);
                qo[grow * NH + col] = f2bf(acc[0][f][r] * 0.125f);
                ko[grow * NH + col] = f2bf(acc[1][f][r]);
                Ls[srow][col] = f2bf(acc[2][f][r]);
            }
        // same-wave LDS RAW (compiler inserts lgkmcnt)
        {
            unsigned short tmp[16];
            #pragma unroll
            for (int j = 0; j < 16; ++j) tmp[j] = Ls[j][lane];
            int b  = mbase >> 12;
            int sb = mbase & (NS - 1);
            unsigned short* dst = vt + ((size_t)(b * NH + lane)) * NS + sb;
            bf16x8 v0, v1;
            #pragma unroll
            for (int j = 0; j < 8; ++j) { v0[j] = (short)tmp[j]; v1[j] = (short)tmp[8 + j]; }
            *(bf16x8*)dst       = v0;
            *(bf16x8*)(dst + 8) = v1;
        }
    }
}

// ---------------------------------------------------------------------------
// Kernel 2: causal flash attention, 4 waves/block, KV-split within block.
// Block owns one 16-row q-tile; wave w does kv-tiles t = w, w+4, ...
// Private (m,l,O) per wave; LDS merge at the end.
// ---------------------------------------------------------------------------
__global__ __launch_bounds__(256) void attn_fwd(
    const unsigned short* __restrict__ q, const unsigned short* __restrict__ k,
    const unsigned short* __restrict__ vt, float* __restrict__ out)
{
    __shared__ unsigned short Ps[4][16][72];
    __shared__ float redO[3][64][16];
    __shared__ float redML[3][64][8];

    const int tid  = threadIdx.x;
    const int lane = tid & 63;
    const int w    = tid >> 6;
    const int lr   = lane & 15;
    const int lg   = lane >> 4;

    // heavy-first: consecutive blockIdx cycle batches, descending q-tile
    const int b  = blockIdx.x & 3;
    const int qt = 255 - (int)(blockIdx.x >> 2);
    const int qb = qt * 16;
    const size_t bq = (size_t)b * NS;

    bf16x8 qf0, qf1;
    {
        const unsigned short* qp = q + (bq + qb + lr) * NH + lg * 8;
        qf0 = *(const bf16x8*)qp;
        qf1 = *(const bf16x8*)(qp + 32);
    }

    f32x4 O[4];
    #pragma unroll
    for (int i = 0; i < 4; ++i) O[i] = (f32x4){0.f, 0.f, 0.f, 0.f};
    float mrow[4], lsum[4];
    #pragma unroll
    for (int r = 0; r < 4; ++r) { mrow[r] = -3.0e38f; lsum[r] = 0.f; }

    const int nt = (qb >> 6) + 1;
    for (int t = w; t < nt; t += 4) {
        const int kvb = t * 64;

        // S = Q K^T
        f32x4 sf[4];
        #pragma unroll
        for (int f = 0; f < 4; ++f) {
            f32x4 s = (f32x4){0.f, 0.f, 0.f, 0.f};
            const unsigned short* kp = k + (bq + kvb + lr + 16 * f) * NH + lg * 8;
            s = MFMA16(qf0, *(const bf16x8*)kp, s);
            s = MFMA16(qf1, *(const bf16x8*)(kp + 32), s);
            sf[f] = s;
        }

        // causal mask (diagonal tile only)
        if (t == nt - 1) {
            #pragma unroll
            for (int f = 0; f < 4; ++f) {
                int kvg = kvb + lr + 16 * f;
                #pragma unroll
                for (int r = 0; r < 4; ++r) {
                    int qg = qb + lg * 4 + r;
                    if (kvg > qg) sf[f][r] = -3.0e38f;
                }
            }
        }

        // online softmax (row r lives in 16-lane group lg)
        #pragma unroll
        for (int r = 0; r < 4; ++r) {
            float pm = fmaxf(fmaxf(sf[0][r], sf[1][r]), fmaxf(sf[2][r], sf[3][r]));
            #pragma unroll
            for (int m = 1; m < 16; m <<= 1) pm = fmaxf(pm, __shfl_xor(pm, m));
            float mnew = fmaxf(mrow[r], pm);
            float corr = __expf(mrow[r] - mnew);
            mrow[r] = mnew;
            float rs = 0.f;
            #pragma unroll
            for (int f = 0; f < 4; ++f) {
                float p = __expf(sf[f][r] - mnew);
                sf[f][r] = p;
                rs += p;
            }
            #pragma unroll
            for (int m = 1; m < 16; m <<= 1) rs += __shfl_xor(rs, m);
            lsum[r] = lsum[r] * corr + rs;
            #pragma unroll
            for (int hf = 0; hf < 4; ++hf) O[hf][r] *= corr;
        }

        // P: C-layout -> wave-private LDS -> A-layout (same-wave, no barrier)
        #pragma unroll
        for (int f = 0; f < 4; ++f)
            #pragma unroll
            for (int r = 0; r < 4; ++r)
                Ps[w][lg * 4 + r][lr + 16 * f] = f2bf(sf[f][r]);

        bf16x8 pa0 = *(const bf16x8*)&Ps[w][lr][lg * 8];
        bf16x8 pa1 = *(const bf16x8*)&Ps[w][lr][lg * 8 + 32];

        // O += P V
        #pragma unroll
        for (int hf = 0; hf < 4; ++hf) {
            const unsigned short* vp = vt + ((size_t)(b * NH + lr + 16 * hf)) * NS + kvb + lg * 8;
            O[hf] = MFMA16(pa0, *(const bf16x8*)vp, O[hf]);
            O[hf] = MFMA16(pa1, *(const bf16x8*)(vp + 32), O[hf]);
        }
    }

    // merge 4 wave-partials
    if (w) {
        #pragma unroll
        for (int hf = 0; hf < 4; ++hf)
            #pragma unroll
            for (int r = 0; r < 4; ++r)
                redO[w - 1][lane][hf * 4 + r] = O[hf][r];
        #pragma unroll
        for (int r = 0; r < 4; ++r) {
            redML[w - 1][lane][r]     = mrow[r];
            redML[w - 1][lane][4 + r] = lsum[r];
        }
    }
    __syncthreads();
    if (w == 0) {
        #pragma unroll
        for (int r = 0; r < 4; ++r) {
            float ms = mrow[r];
            #pragma unroll
            for (int ww = 0; ww < 3; ++ww) ms = fmaxf(ms, redML[ww][lane][r]);
            float c0 = __expf(mrow[r] - ms);
            float l = lsum[r] * c0;
            float o[4];
            #pragma unroll
            for (int hf = 0; hf < 4; ++hf) o[hf] = O[hf][r] * c0;
            #pragma unroll
            for (int ww = 0; ww < 3; ++ww) {
                float cw = __expf(redML[ww][lane][r] - ms);
                l += redML[ww][lane][4 + r] * cw;
                #pragma unroll
                for (int hf = 0; hf < 4; ++hf)
                    o[hf] += redO[ww][lane][hf * 4 + r] * cw;
            }
            float inv = 1.f / l;
            float* op = out + (bq + qb + lg * 4 + r) * NH + lr;
            #pragma unroll
            for (int hf = 0; hf < 4; ++hf) op[16 * hf] = o[hf] * inv;
        }
    }
}

extern "C" void kernel_launch(void* const* d_in, const int* in_sizes, int n_in,
                              void* d_out, int out_size, void* d_ws, size_t ws_size,
                              hipStream_t stream)
{
    const float* x  = (const float*)d_in[0];
    const float* Wq = (const float*)d_in[1];
    const float* Wk = (const float*)d_in[2];
    const float* Wv = (const float*)d_in[3];
    float* out = (float*)d_out;

    const size_t n = (size_t)NB * NS * NH;          // 1M elements per tensor
    unsigned short* qb = (unsigned short*)d_ws;     // 2 MB
    unsigned short* kb = qb + n;                    // 2 MB
    unsigned short* vT = kb + n;                    // 2 MB (layout [b][h][s])
    unsigned short* wT = vT + n;                    // 384 KB (layout [m][n][k])

    wconv<<<dim3(3 * NH), dim3(256), 0, stream>>>(Wq, Wk, Wv, wT);
    qkv_proj<<<dim3((NB * NS) / 16), dim3(256), 0, stream>>>(x, wT, qb, kb, vT);
    attn_fwd<<<dim3(NB * (NS / 16)), dim3(256), 0, stream>>>(qb, kb, vT, out);
}

// Round 3
// 87.847 us; speedup vs baseline: 2.5340x; 1.5099x over previous
//
#include <hip/hip_runtime.h>

typedef __attribute__((ext_vector_type(8))) short bf16x8;
typedef __attribute__((ext_vector_type(4))) float f32x4;

#define MFMA16(A, Bv, C) __builtin_amdgcn_mfma_f32_16x16x32_bf16((A), (Bv), (C), 0, 0, 0)

static constexpr int NB = 4, NS = 4096, ND = 1024, NH = 64;

__device__ __forceinline__ unsigned short f2bf(float f) {
    union { float f; unsigned int u; } x; x.f = f;
    unsigned int r = x.u + 0x7fffu + ((x.u >> 16) & 1u);
    return (unsigned short)(r >> 16);
}

// async global->LDS, 16B per lane; LDS dest = wave-uniform base + lane*16
__device__ __forceinline__ void gload_lds16(const void* g, void* l) {
    __builtin_amdgcn_global_load_lds((const __attribute__((address_space(1))) void*)g,
                                     (__attribute__((address_space(3))) void*)l, 16, 0, 0);
}

// ---------------------------------------------------------------------------
// Kernel 0: W[D][H] fp32 -> wT[m*64+n][k] bf16  (192 x 1024, 384 KB, L2-hot)
// ---------------------------------------------------------------------------
__global__ __launch_bounds__(256) void wconv(
    const float* __restrict__ Wq, const float* __restrict__ Wk,
    const float* __restrict__ Wv, unsigned short* __restrict__ wT)
{
    int mn = blockIdx.x;                 // 0..191 = m*64 + n
    int m = mn >> 6, n = mn & 63;
    const float* W = (m == 0) ? Wq : (m == 1) ? Wk : Wv;
    unsigned short* dst = wT + (size_t)mn * ND;
    for (int k = threadIdx.x; k < ND; k += 256)
        dst[k] = f2bf(W[(size_t)k * NH + n]);
}

// ---------------------------------------------------------------------------
// Kernel 1: QKV projection. Block = 4 waves = 64 rows (wave w -> 16-row M-frag,
// full K). wT k-slice (192x32, 12KB) staged dbuf in LDS via global_load_lds,
// shared by all 4 waves. x software-pipelined in registers. 1 barrier/k-step.
// LDS chunk swizzle: chunk' = chunk ^ (row&3) on both stage-source and read.
// ---------------------------------------------------------------------------
__global__ __launch_bounds__(256) void qkv_proj(
    const float* __restrict__ x, const unsigned short* __restrict__ wT,
    unsigned short* __restrict__ qo, unsigned short* __restrict__ ko,
    unsigned short* __restrict__ vt)
{
    __shared__ unsigned short Ws[2][192][32];   // [buf][n-row][k-chunk], row = 64B
    __shared__ unsigned short Ls[4][16][72];    // per-wave v transpose staging

    const int tid  = threadIdx.x;
    const int lane = tid & 63;
    const int w    = tid >> 6;
    const int lr   = lane & 15;
    const int lg   = lane >> 4;
    const int mbase = blockIdx.x * 64;

    // stage lane mapping: 1 instr = 16 rows x 64B; lane -> row lane>>2, chunk lane&3
    const int srow = lane >> 2;
    const int schk = (lane & 3) ^ (srow & 3);   // pre-swizzled source chunk

    f32x4 acc[12];
    #pragma unroll
    for (int i = 0; i < 12; ++i) acc[i] = (f32x4){0.f, 0.f, 0.f, 0.f};

    const float* xrow = x + (size_t)(mbase + w * 16 + lr) * ND + lg * 8;

    // stage k-step kt into buffer buf (3 instrs per wave, 12 total = 192 rows)
    #define STAGEW(buf, kt)                                                          \
        do {                                                                         \
            _Pragma("unroll")                                                        \
            for (int i_ = 0; i_ < 3; ++i_) {                                         \
                int rbase_ = w * 48 + i_ * 16;                                       \
                const unsigned short* src_ =                                         \
                    wT + (size_t)(rbase_ + srow) * ND + (kt) * 32 + schk * 8;        \
                gload_lds16(src_, &Ws[buf][rbase_][0]);                              \
            }                                                                        \
        } while (0)

    // prologue: stage k-step 0, load x for step 0
    STAGEW(0, 0);
    float4 cu0 = *(const float4*)xrow;
    float4 cu1 = *(const float4*)(xrow + 4);
    __syncthreads();

    int cur = 0;
    for (int kt = 0; kt < 32; ++kt) {
        // issue next stage + next x loads first (overlap with compute)
        if (kt + 1 < 32) STAGEW(cur ^ 1, kt + 1);
        float4 nu0, nu1;
        if (kt + 1 < 32) {
            const float* xp = xrow + (kt + 1) * 32;
            nu0 = *(const float4*)xp;
            nu1 = *(const float4*)(xp + 4);
        }

        bf16x8 a;
        a[0] = (short)f2bf(cu0.x); a[1] = (short)f2bf(cu0.y);
        a[2] = (short)f2bf(cu0.z); a[3] = (short)f2bf(cu0.w);
        a[4] = (short)f2bf(cu1.x); a[5] = (short)f2bf(cu1.y);
        a[6] = (short)f2bf(cu1.z); a[7] = (short)f2bf(cu1.w);

        #pragma unroll
        for (int mf = 0; mf < 12; ++mf) {        // n-row = mf*16 + lr
            int row = mf * 16 + lr;
            bf16x8 bfr = *(const bf16x8*)&Ws[cur][row][((lg ^ (lr & 3))) * 8];
            acc[mf] = MFMA16(a, bfr, acc[mf]);
        }
        __syncthreads();
        cur ^= 1;
        cu0 = nu0; cu1 = nu1;
    }

    // per-wave epilogue: q (scaled), k row-major; v -> LDS -> vT[b][h][s]
    #pragma unroll
    for (int f = 0; f < 4; ++f)
        #pragma unroll
        for (int r = 0; r < 4; ++r) {
            int srw = lg * 4 + r;                 // C/D: row=(lane>>4)*4+reg
            int col = lr + 16 * f;                //      col=lane&15
            size_t grow = (size_t)(mbase + w * 16 + srw);
            qo[grow * NH + col] = f2bf(acc[f][r] * 0.125f);
            ko[grow * NH + col] = f2bf(acc[4 + f][r]);
            Ls[w][srw][col] = f2bf(acc[8 + f][r]);
        }
    {   // same-wave LDS transpose (compiler handles lgkmcnt)
        unsigned short tmp[16];
        #pragma unroll
        for (int jj = 0; jj < 16; ++jj) tmp[jj] = Ls[w][jj][lane];
        int b_ = mbase >> 12;
        int sb = (mbase & (NS - 1)) + w * 16;
        unsigned short* dst = vt + ((size_t)(b_ * NH + lane)) * NS + sb;
        bf16x8 v0, v1;
        #pragma unroll
        for (int jj = 0; jj < 8; ++jj) { v0[jj] = (short)tmp[jj]; v1[jj] = (short)tmp[8 + jj]; }
        *(bf16x8*)dst       = v0;
        *(bf16x8*)(dst + 8) = v1;
    }
    #undef STAGEW
}

// ---------------------------------------------------------------------------
// Kernel 2: attention phase A (flash-decode, chunked).
// Unit = (batch b, 64-q-row block j, kv-chunk c of 8 tiles = 512 kv).
// 4 waves: wave w owns q-frag rows j*64+w*16..+16 for ALL tiles of the chunk.
// K/V tiles staged dbuf in LDS (global_load_lds, XOR chunk swizzle), shared.
// Writes unnormalized partial (O, m, l) to workspace.
// ---------------------------------------------------------------------------
__global__ __launch_bounds__(256) void attn_part(
    const unsigned short* __restrict__ q, const unsigned short* __restrict__ k,
    const unsigned short* __restrict__ vt, float* __restrict__ pO,
    float* __restrict__ pm, float* __restrict__ pl)
{
    __shared__ unsigned short Kt[2][64][64];   // [buf][kv][d], swizzled chunks
    __shared__ unsigned short Vt[2][64][64];   // [buf][h][kv], swizzled chunks
    __shared__ unsigned short Ps[4][16][72];

    const int bid = blockIdx.x;
    const int b = bid & 3;
    const int j = (bid >> 2) & 63;
    const int c = bid >> 8;                    // 0..7
    if (c > (j >> 3)) return;                  // dead block (beyond causal extent)
    const int ntile = (j + 1 - c * 8 < 8) ? (j + 1 - c * 8) : 8;
    const int tg0 = c * 8;

    const int tid  = threadIdx.x;
    const int lane = tid & 63;
    const int w    = tid >> 6;
    const int lr   = lane & 15;
    const int lg   = lane >> 4;
    const size_t bq = (size_t)b * NS;
    const int qb = j * 64;

    // stage lane mapping: 1 instr = 8 rows x 128B; lane -> row lane>>3, chunk lane&7
    const int srow = lane >> 3;
    const int schk = (lane & 7) ^ srow;        // pre-swizzled source chunk

    #define STAGEKV(buf, tg)                                                          \
        do {                                                                          \
            int kvb_ = (tg) * 64;                                                     \
            if (w < 2) {                                                              \
                _Pragma("unroll")                                                     \
                for (int i_ = 0; i_ < 4; ++i_) {                                      \
                    int rb_ = w * 32 + i_ * 8;                                        \
                    const unsigned short* src_ =                                      \
                        k + (bq + kvb_ + rb_ + srow) * NH + schk * 8;                 \
                    gload_lds16(src_, &Kt[buf][rb_][0]);                              \
                }                                                                     \
            } else {                                                                  \
                _Pragma("unroll")                                                     \
                for (int i_ = 0; i_ < 4; ++i_) {                                      \
                    int rb_ = (w - 2) * 32 + i_ * 8;                                  \
                    const unsigned short* src_ =                                      \
                        vt + ((size_t)(b * NH + rb_ + srow)) * NS + kvb_ + schk * 8;  \
                    gload_lds16(src_, &Vt[buf][rb_][0]);                              \
                }                                                                     \
            }                                                                         \
        } while (0)

    // Q frags (16 rows per wave)
    bf16x8 qf0, qf1;
    {
        const unsigned short* qp = q + (bq + qb + w * 16 + lr) * NH + lg * 8;
        qf0 = *(const bf16x8*)qp;
        qf1 = *(const bf16x8*)(qp + 32);
    }

    f32x4 O[4];
    #pragma unroll
    for (int i = 0; i < 4; ++i) O[i] = (f32x4){0.f, 0.f, 0.f, 0.f};
    float mrow[4], lsum[4];
    #pragma unroll
    for (int r = 0; r < 4; ++r) { mrow[r] = -3.0e38f; lsum[r] = 0.f; }

    STAGEKV(0, tg0);
    __syncthreads();

    int cur = 0;
    for (int t = 0; t < ntile; ++t) {
        const int tg = tg0 + t;
        // issue next stage first (dummy re-stage of tg0 on last iter keeps code uniform)
        STAGEKV(cur ^ 1, (t + 1 < ntile) ? tg + 1 : tg0);

        // S = Q K^T from staged K tile
        f32x4 sf[4];
        #pragma unroll
        for (int f = 0; f < 4; ++f) {
            f32x4 s = (f32x4){0.f, 0.f, 0.f, 0.f};
            int row = f * 16 + lr;
            bf16x8 kb0 = *(const bf16x8*)&Kt[cur][row][((lg    ) ^ (lr & 7)) * 8];
            bf16x8 kb1 = *(const bf16x8*)&Kt[cur][row][((lg + 4) ^ (lr & 7)) * 8];
            s = MFMA16(qf0, kb0, s);
            s = MFMA16(qf1, kb1, s);
            sf[f] = s;
        }

        // causal mask: only the diagonal block tile (tg == j)
        if (tg == j) {
            #pragma unroll
            for (int f = 0; f < 4; ++f) {
                int kvl = f * 16 + lr;
                #pragma unroll
                for (int r = 0; r < 4; ++r) {
                    int ql = w * 16 + lg * 4 + r;
                    if (kvl > ql) sf[f][r] = -3.0e38f;
                }
            }
        }

        // online softmax (row r lives in 16-lane group lg)
        #pragma unroll
        for (int r = 0; r < 4; ++r) {
            float pmx = fmaxf(fmaxf(sf[0][r], sf[1][r]), fmaxf(sf[2][r], sf[3][r]));
            #pragma unroll
            for (int mm = 1; mm < 16; mm <<= 1) pmx = fmaxf(pmx, __shfl_xor(pmx, mm));
            float mnew = fmaxf(mrow[r], pmx);
            float corr = __expf(mrow[r] - mnew);
            mrow[r] = mnew;
            float rs = 0.f;
            #pragma unroll
            for (int f = 0; f < 4; ++f) {
                float p = __expf(sf[f][r] - mnew);
                sf[f][r] = p;
                rs += p;
            }
            #pragma unroll
            for (int mm = 1; mm < 16; mm <<= 1) rs += __shfl_xor(rs, mm);
            lsum[r] = lsum[r] * corr + rs;
            #pragma unroll
            for (int hf = 0; hf < 4; ++hf) O[hf][r] *= corr;
        }

        // P: C-layout -> wave-private LDS -> A-layout (same-wave)
        #pragma unroll
        for (int f = 0; f < 4; ++f)
            #pragma unroll
            for (int r = 0; r < 4; ++r)
                Ps[w][lg * 4 + r][lr + 16 * f] = f2bf(sf[f][r]);

        bf16x8 pa0 = *(const bf16x8*)&Ps[w][lr][lg * 8];
        bf16x8 pa1 = *(const bf16x8*)&Ps[w][lr][lg * 8 + 32];

        // O += P V from staged V tile
        #pragma unroll
        for (int hf = 0; hf < 4; ++hf) {
            int row = hf * 16 + lr;
            bf16x8 vb0 = *(const bf16x8*)&Vt[cur][row][((lg    ) ^ (lr & 7)) * 8];
            bf16x8 vb1 = *(const bf16x8*)&Vt[cur][row][((lg + 4) ^ (lr & 7)) * 8];
            O[hf] = MFMA16(pa0, vb0, O[hf]);
            O[hf] = MFMA16(pa1, vb1, O[hf]);
        }

        __syncthreads();   // stage(t+1) landed (drain) + all reads of cur done
        cur ^= 1;
    }

    // write partial: pidx = b*288 + prefix(j) + c, prefix(j) = (a+1)(4a+r), j=8a+r
    const int a8 = j >> 3, r8 = j & 7;
    const int pidx = b * 288 + (a8 + 1) * (4 * a8 + r8) + c;
    float* Po = pO + (size_t)pidx * 4096;
    #pragma unroll
    for (int hf = 0; hf < 4; ++hf)
        #pragma unroll
        for (int r = 0; r < 4; ++r)
            Po[(w * 16 + lg * 4 + r) * 64 + lr + 16 * hf] = O[hf][r];
    if (lr == 0) {
        #pragma unroll
        for (int r = 0; r < 4; ++r) {
            pm[pidx * 64 + w * 16 + lg * 4 + r] = mrow[r];
            pl[pidx * 64 + w * 16 + lg * 4 + r] = lsum[r];
        }
    }
    #undef STAGEKV
}

// ---------------------------------------------------------------------------
// Kernel 3: attention phase B — merge chunk partials (exact online-softmax).
// Block = (b, j); thread -> (row, 16-h slice); <=8 chunks.
// ---------------------------------------------------------------------------
__global__ __launch_bounds__(256) void attn_merge(
    const float* __restrict__ pO, const float* __restrict__ pm,
    const float* __restrict__ pl, float* __restrict__ out)
{
    const int bid = blockIdx.x;
    const int b = bid & 3, j = bid >> 2;
    const int nch = (j >> 3) + 1;
    const int a8 = j >> 3, r8 = j & 7;
    const int pbase = b * 288 + (a8 + 1) * (4 * a8 + r8);
    const int tid = threadIdx.x;
    const int row = tid >> 2, hq = (tid & 3) * 16;

    float M = -3.0e38f, L = 0.f;
    f32x4 acc0 = {0,0,0,0}, acc1 = {0,0,0,0}, acc2 = {0,0,0,0}, acc3 = {0,0,0,0};
    for (int cc = 0; cc < nch; ++cc) {
        int pidx = pbase + cc;
        float mc = pm[pidx * 64 + row];
        float lc = pl[pidx * 64 + row];
        const f32x4* po = (const f32x4*)(pO + (size_t)pidx * 4096 + row * 64 + hq);
        float Mn = fmaxf(M, mc);
        float sO = __expf(M - Mn), sN = __expf(mc - Mn);
        L = L * sO + lc * sN;
        acc0 = acc0 * sO + po[0] * sN;
        acc1 = acc1 * sO + po[1] * sN;
        acc2 = acc2 * sO + po[2] * sN;
        acc3 = acc3 * sO + po[3] * sN;
        M = Mn;
    }
    float inv = 1.f / L;
    float* op = out + ((size_t)b * NS + (size_t)j * 64 + row) * NH + hq;
    *(f32x4*)(op + 0)  = acc0 * inv;
    *(f32x4*)(op + 4)  = acc1 * inv;
    *(f32x4*)(op + 8)  = acc2 * inv;
    *(f32x4*)(op + 12) = acc3 * inv;
}

extern "C" void kernel_launch(void* const* d_in, const int* in_sizes, int n_in,
                              void* d_out, int out_size, void* d_ws, size_t ws_size,
                              hipStream_t stream)
{
    const float* x  = (const float*)d_in[0];
    const float* Wq = (const float*)d_in[1];
    const float* Wk = (const float*)d_in[2];
    const float* Wv = (const float*)d_in[3];
    float* out = (float*)d_out;

    const size_t n = (size_t)NB * NS * NH;            // 1,048,576 elements
    unsigned short* qb_ = (unsigned short*)d_ws;      // 2 MB
    unsigned short* kb_ = qb_ + n;                    // 2 MB
    unsigned short* vT  = kb_ + n;                    // 2 MB (layout [b][h][s])
    unsigned short* wT  = vT + n;                     // 384 KB (layout [192][1024])
    float* pO  = (float*)(wT + 192 * 1024);           // 1152 x 4096 f32 = 18.9 MB
    float* pm_ = pO + (size_t)1152 * 4096;            // 1152 x 64 f32
    float* pl_ = pm_ + 1152 * 64;                     // 1152 x 64 f32

    wconv<<<dim3(192), dim3(256), 0, stream>>>(Wq, Wk, Wv, wT);
    qkv_proj<<<dim3(256), dim3(256), 0, stream>>>(x, wT, qb_, kb_, vT);
    attn_part<<<dim3(2048), dim3(256), 0, stream>>>(qb_, kb_, vT, pO, pm_, pl_);
    attn_merge<<<dim3(256), dim3(256), 0, stream>>>(pO, pm_, pl_, out);
}

// Round 4
// 85.747 us; speedup vs baseline: 2.5961x; 1.0245x over previous
//
#include <hip/hip_runtime.h>

typedef __attribute__((ext_vector_type(8))) short bf16x8;
typedef __attribute__((ext_vector_type(4))) float f32x4;

#define MFMA16(A, Bv, C) __builtin_amdgcn_mfma_f32_16x16x32_bf16((A), (Bv), (C), 0, 0, 0)

static constexpr int NB = 4, NS = 4096, ND = 1024, NH = 64;

__device__ __forceinline__ unsigned short f2bf(float f) {
    union { float f; unsigned int u; } x; x.f = f;
    unsigned int r = x.u + 0x7fffu + ((x.u >> 16) & 1u);
    return (unsigned short)(r >> 16);
}

// async global->LDS, 16B per lane; LDS dest = wave-uniform base + lane*16
__device__ __forceinline__ void gload_lds16(const void* g, void* l) {
    __builtin_amdgcn_global_load_lds((const __attribute__((address_space(1))) void*)g,
                                     (__attribute__((address_space(3))) void*)l, 16, 0, 0);
}

// ---------------------------------------------------------------------------
// Kernel 0: W[D][H] fp32 -> wT[m*64+n][k] bf16  (192 x 1024, 384 KB, L2-hot)
// ---------------------------------------------------------------------------
__global__ __launch_bounds__(256) void wconv(
    const float* __restrict__ Wq, const float* __restrict__ Wk,
    const float* __restrict__ Wv, unsigned short* __restrict__ wT)
{
    int mn = blockIdx.x;                 // 0..191 = m*64 + n
    int m = mn >> 6, n = mn & 63;
    const float* W = (m == 0) ? Wq : (m == 1) ? Wk : Wv;
    unsigned short* dst = wT + (size_t)mn * ND;
    for (int k = threadIdx.x; k < ND; k += 256)
        dst[k] = f2bf(W[(size_t)k * NH + n]);
}

// ---------------------------------------------------------------------------
// Kernel 1: QKV projection. Block = 32 rows, 512 blocks (2/CU for TLP).
// Wave w -> row-frag rf=w&1 (16 rows), col-half cg=w>>1 (cols cg*32..+32 of
// each of q,k,v). wT k-slice (192x32, 12KB) staged dbuf in LDS via
// global_load_lds (shared by all 4 waves); x software-pipelined in registers.
// 1 barrier/k-step; stage+x-loads issued BEFORE compute so the end-of-step
// drain overlaps the other resident block's compute phase.
// ---------------------------------------------------------------------------
__global__ __launch_bounds__(256) void qkv_proj(
    const float* __restrict__ x, const unsigned short* __restrict__ wT,
    unsigned short* __restrict__ qo, unsigned short* __restrict__ ko,
    unsigned short* __restrict__ vt)
{
    __shared__ unsigned short Ws[2][192][32];   // [buf][n-row][k], row = 64B
    __shared__ unsigned short Ls[32][72];       // v transpose staging

    const int tid  = threadIdx.x;
    const int lane = tid & 63;
    const int w    = tid >> 6;
    const int lr   = lane & 15;
    const int lg   = lane >> 4;
    const int rf   = w & 1;                     // row-frag
    const int cg   = w >> 1;                    // col half
    const int mbase = blockIdx.x * 32;

    // stage lane mapping: 1 instr = 16 rows x 64B; lane -> row lane>>2, chunk lane&3
    const int srow = lane >> 2;
    const int schk = (lane & 3) ^ (srow & 3);   // pre-swizzled source chunk

    f32x4 acc[6];                               // [m*2+fi]
    #pragma unroll
    for (int i = 0; i < 6; ++i) acc[i] = (f32x4){0.f, 0.f, 0.f, 0.f};

    const float* xrow = x + (size_t)(mbase + rf * 16 + lr) * ND + lg * 8;

    // stage k-step kt into buffer buf (3 instrs per wave, 12 total = 192 rows)
    #define STAGEW(buf, kt)                                                          \
        do {                                                                         \
            _Pragma("unroll")                                                        \
            for (int i_ = 0; i_ < 3; ++i_) {                                         \
                int rbase_ = w * 48 + i_ * 16;                                       \
                const unsigned short* src_ =                                         \
                    wT + (size_t)(rbase_ + srow) * ND + (kt) * 32 + schk * 8;        \
                gload_lds16(src_, &Ws[buf][rbase_][0]);                              \
            }                                                                        \
        } while (0)

    // prologue: stage k-step 0, load x for step 0
    STAGEW(0, 0);
    float4 cu0 = *(const float4*)xrow;
    float4 cu1 = *(const float4*)(xrow + 4);
    __syncthreads();

    int cur = 0;
    for (int kt = 0; kt < 32; ++kt) {
        // issue next stage + next x loads first (overlap with compute)
        if (kt + 1 < 32) STAGEW(cur ^ 1, kt + 1);
        float4 nu0, nu1;
        if (kt + 1 < 32) {
            const float* xp = xrow + (kt + 1) * 32;
            nu0 = *(const float4*)xp;
            nu1 = *(const float4*)(xp + 4);
        }

        bf16x8 a;
        a[0] = (short)f2bf(cu0.x); a[1] = (short)f2bf(cu0.y);
        a[2] = (short)f2bf(cu0.z); a[3] = (short)f2bf(cu0.w);
        a[4] = (short)f2bf(cu1.x); a[5] = (short)f2bf(cu1.y);
        a[6] = (short)f2bf(cu1.z); a[7] = (short)f2bf(cu1.w);

        #pragma unroll
        for (int m = 0; m < 3; ++m)
            #pragma unroll
            for (int fi = 0; fi < 2; ++fi) {
                int row = m * 64 + (cg * 2 + fi) * 16 + lr;
                bf16x8 bfr = *(const bf16x8*)&Ws[cur][row][((lg ^ (lr & 3))) * 8];
                acc[m * 2 + fi] = MFMA16(a, bfr, acc[m * 2 + fi]);
            }
        __syncthreads();
        cur ^= 1;
        cu0 = nu0; cu1 = nu1;
    }

    // epilogue: q (scaled), k row-major; v -> LDS -> transposed vT[b][h][s]
    #pragma unroll
    for (int fi = 0; fi < 2; ++fi)
        #pragma unroll
        for (int r = 0; r < 4; ++r) {
            int srw = lg * 4 + r;                 // C/D: row=(lane>>4)*4+reg
            int col = (cg * 2 + fi) * 16 + lr;    //      col=lane&15
            size_t grow = (size_t)(mbase + rf * 16 + srw);
            qo[grow * NH + col] = f2bf(acc[fi][r] * 0.125f);
            ko[grow * NH + col] = f2bf(acc[2 + fi][r]);
            Ls[rf * 16 + srw][col] = f2bf(acc[4 + fi][r]);
        }
    __syncthreads();
    {   // transpose 32 s x 64 h: thread -> (h, 8-s strip)
        int h  = tid >> 2;
        int so = (tid & 3) * 8;
        unsigned short tmp[8];
        #pragma unroll
        for (int jj = 0; jj < 8; ++jj) tmp[jj] = Ls[so + jj][h];
        int b_ = mbase >> 12;
        int sb = (mbase & (NS - 1)) + so;
        unsigned short* dst = vt + ((size_t)(b_ * NH + h)) * NS + sb;
        bf16x8 v0;
        #pragma unroll
        for (int jj = 0; jj < 8; ++jj) v0[jj] = (short)tmp[jj];
        *(bf16x8*)dst = v0;
    }
    #undef STAGEW
}

// ---------------------------------------------------------------------------
// Kernel 2: attention phase A (flash-decode, chunked).
// Unit = (batch b, 64-q-row block j, kv-chunk c of 8 tiles = 512 kv).
// 4 waves: wave w owns q-frag rows j*64+w*16..+16 for ALL tiles of the chunk.
// K/V tiles staged dbuf in LDS (global_load_lds, XOR chunk swizzle), shared.
// Writes unnormalized partial (O, m, l) to workspace.
// ---------------------------------------------------------------------------
__global__ __launch_bounds__(256) void attn_part(
    const unsigned short* __restrict__ q, const unsigned short* __restrict__ k,
    const unsigned short* __restrict__ vt, float* __restrict__ pO,
    float* __restrict__ pm, float* __restrict__ pl)
{
    __shared__ unsigned short Kt[2][64][64];   // [buf][kv][d], swizzled chunks
    __shared__ unsigned short Vt[2][64][64];   // [buf][h][kv], swizzled chunks
    __shared__ unsigned short Ps[4][16][72];

    const int bid = blockIdx.x;
    const int b = bid & 3;
    const int j = (bid >> 2) & 63;
    const int c = bid >> 8;                    // 0..7
    if (c > (j >> 3)) return;                  // dead block (beyond causal extent)
    const int ntile = (j + 1 - c * 8 < 8) ? (j + 1 - c * 8) : 8;
    const int tg0 = c * 8;

    const int tid  = threadIdx.x;
    const int lane = tid & 63;
    const int w    = tid >> 6;
    const int lr   = lane & 15;
    const int lg   = lane >> 4;
    const size_t bq = (size_t)b * NS;
    const int qb = j * 64;

    // stage lane mapping: 1 instr = 8 rows x 128B; lane -> row lane>>3, chunk lane&7
    const int srow = lane >> 3;
    const int schk = (lane & 7) ^ srow;        // pre-swizzled source chunk

    #define STAGEKV(buf, tg)                                                          \
        do {                                                                          \
            int kvb_ = (tg) * 64;                                                     \
            if (w < 2) {                                                              \
                _Pragma("unroll")                                                     \
                for (int i_ = 0; i_ < 4; ++i_) {                                      \
                    int rb_ = w * 32 + i_ * 8;                                        \
                    const unsigned short* src_ =                                      \
                        k + (bq + kvb_ + rb_ + srow) * NH + schk * 8;                 \
                    gload_lds16(src_, &Kt[buf][rb_][0]);                              \
                }                                                                     \
            } else {                                                                  \
                _Pragma("unroll")                                                     \
                for (int i_ = 0; i_ < 4; ++i_) {                                      \
                    int rb_ = (w - 2) * 32 + i_ * 8;                                  \
                    const unsigned short* src_ =                                      \
                        vt + ((size_t)(b * NH + rb_ + srow)) * NS + kvb_ + schk * 8;  \
                    gload_lds16(src_, &Vt[buf][rb_][0]);                              \
                }                                                                     \
            }                                                                         \
        } while (0)

    // Q frags (16 rows per wave)
    bf16x8 qf0, qf1;
    {
        const unsigned short* qp = q + (bq + qb + w * 16 + lr) * NH + lg * 8;
        qf0 = *(const bf16x8*)qp;
        qf1 = *(const bf16x8*)(qp + 32);
    }

    f32x4 O[4];
    #pragma unroll
    for (int i = 0; i < 4; ++i) O[i] = (f32x4){0.f, 0.f, 0.f, 0.f};
    float mrow[4], lsum[4];
    #pragma unroll
    for (int r = 0; r < 4; ++r) { mrow[r] = -3.0e38f; lsum[r] = 0.f; }

    STAGEKV(0, tg0);
    __syncthreads();

    int cur = 0;
    for (int t = 0; t < ntile; ++t) {
        const int tg = tg0 + t;
        // issue next stage first (dummy re-stage of tg0 on last iter keeps code uniform)
        STAGEKV(cur ^ 1, (t + 1 < ntile) ? tg + 1 : tg0);

        // S = Q K^T from staged K tile
        f32x4 sf[4];
        #pragma unroll
        for (int f = 0; f < 4; ++f) {
            f32x4 s = (f32x4){0.f, 0.f, 0.f, 0.f};
            int row = f * 16 + lr;
            bf16x8 kb0 = *(const bf16x8*)&Kt[cur][row][((lg    ) ^ (lr & 7)) * 8];
            bf16x8 kb1 = *(const bf16x8*)&Kt[cur][row][((lg + 4) ^ (lr & 7)) * 8];
            s = MFMA16(qf0, kb0, s);
            s = MFMA16(qf1, kb1, s);
            sf[f] = s;
        }

        // causal mask: only the diagonal block tile (tg == j)
        if (tg == j) {
            #pragma unroll
            for (int f = 0; f < 4; ++f) {
                int kvl = f * 16 + lr;
                #pragma unroll
                for (int r = 0; r < 4; ++r) {
                    int ql = w * 16 + lg * 4 + r;
                    if (kvl > ql) sf[f][r] = -3.0e38f;
                }
            }
        }

        // online softmax (row r lives in 16-lane group lg)
        #pragma unroll
        for (int r = 0; r < 4; ++r) {
            float pmx = fmaxf(fmaxf(sf[0][r], sf[1][r]), fmaxf(sf[2][r], sf[3][r]));
            #pragma unroll
            for (int mm = 1; mm < 16; mm <<= 1) pmx = fmaxf(pmx, __shfl_xor(pmx, mm));
            float mnew = fmaxf(mrow[r], pmx);
            float corr = __expf(mrow[r] - mnew);
            mrow[r] = mnew;
            float rs = 0.f;
            #pragma unroll
            for (int f = 0; f < 4; ++f) {
                float p = __expf(sf[f][r] - mnew);
                sf[f][r] = p;
                rs += p;
            }
            #pragma unroll
            for (int mm = 1; mm < 16; mm <<= 1) rs += __shfl_xor(rs, mm);
            lsum[r] = lsum[r] * corr + rs;
            #pragma unroll
            for (int hf = 0; hf < 4; ++hf) O[hf][r] *= corr;
        }

        // P: C-layout -> wave-private LDS -> A-layout (same-wave)
        #pragma unroll
        for (int f = 0; f < 4; ++f)
            #pragma unroll
            for (int r = 0; r < 4; ++r)
                Ps[w][lg * 4 + r][lr + 16 * f] = f2bf(sf[f][r]);

        bf16x8 pa0 = *(const bf16x8*)&Ps[w][lr][lg * 8];
        bf16x8 pa1 = *(const bf16x8*)&Ps[w][lr][lg * 8 + 32];

        // O += P V from staged V tile
        #pragma unroll
        for (int hf = 0; hf < 4; ++hf) {
            int row = hf * 16 + lr;
            bf16x8 vb0 = *(const bf16x8*)&Vt[cur][row][((lg    ) ^ (lr & 7)) * 8];
            bf16x8 vb1 = *(const bf16x8*)&Vt[cur][row][((lg + 4) ^ (lr & 7)) * 8];
            O[hf] = MFMA16(pa0, vb0, O[hf]);
            O[hf] = MFMA16(pa1, vb1, O[hf]);
        }

        __syncthreads();   // stage(t+1) landed (drain) + all reads of cur done
        cur ^= 1;
    }

    // write partial: pidx = b*288 + prefix(j) + c, prefix(j) = (a+1)(4a+r), j=8a+r
    const int a8 = j >> 3, r8 = j & 7;
    const int pidx = b * 288 + (a8 + 1) * (4 * a8 + r8) + c;
    float* Po = pO + (size_t)pidx * 4096;
    #pragma unroll
    for (int hf = 0; hf < 4; ++hf)
        #pragma unroll
        for (int r = 0; r < 4; ++r)
            Po[(w * 16 + lg * 4 + r) * 64 + lr + 16 * hf] = O[hf][r];
    if (lr == 0) {
        #pragma unroll
        for (int r = 0; r < 4; ++r) {
            pm[pidx * 64 + w * 16 + lg * 4 + r] = mrow[r];
            pl[pidx * 64 + w * 16 + lg * 4 + r] = lsum[r];
        }
    }
    #undef STAGEKV
}

// ---------------------------------------------------------------------------
// Kernel 3: attention phase B — merge chunk partials (exact online-softmax).
// Block = (b, j); thread -> (row, 16-h slice); <=8 chunks.
// ---------------------------------------------------------------------------
__global__ __launch_bounds__(256) void attn_merge(
    const float* __restrict__ pO, const float* __restrict__ pm,
    const float* __restrict__ pl, float* __restrict__ out)
{
    const int bid = blockIdx.x;
    const int b = bid & 3, j = bid >> 2;
    const int nch = (j >> 3) + 1;
    const int a8 = j >> 3, r8 = j & 7;
    const int pbase = b * 288 + (a8 + 1) * (4 * a8 + r8);
    const int tid = threadIdx.x;
    const int row = tid >> 2, hq = (tid & 3) * 16;

    float M = -3.0e38f, L = 0.f;
    f32x4 acc0 = {0,0,0,0}, acc1 = {0,0,0,0}, acc2 = {0,0,0,0}, acc3 = {0,0,0,0};
    for (int cc = 0; cc < nch; ++cc) {
        int pidx = pbase + cc;
        float mc = pm[pidx * 64 + row];
        float lc = pl[pidx * 64 + row];
        const f32x4* po = (const f32x4*)(pO + (size_t)pidx * 4096 + row * 64 + hq);
        float Mn = fmaxf(M, mc);
        float sO = __expf(M - Mn), sN = __expf(mc - Mn);
        L = L * sO + lc * sN;
        acc0 = acc0 * sO + po[0] * sN;
        acc1 = acc1 * sO + po[1] * sN;
        acc2 = acc2 * sO + po[2] * sN;
        acc3 = acc3 * sO + po[3] * sN;
        M = Mn;
    }
    float inv = 1.f / L;
    float* op = out + ((size_t)b * NS + (size_t)j * 64 + row) * NH + hq;
    *(f32x4*)(op + 0)  = acc0 * inv;
    *(f32x4*)(op + 4)  = acc1 * inv;
    *(f32x4*)(op + 8)  = acc2 * inv;
    *(f32x4*)(op + 12) = acc3 * inv;
}

extern "C" void kernel_launch(void* const* d_in, const int* in_sizes, int n_in,
                              void* d_out, int out_size, void* d_ws, size_t ws_size,
                              hipStream_t stream)
{
    const float* x  = (const float*)d_in[0];
    const float* Wq = (const float*)d_in[1];
    const float* Wk = (const float*)d_in[2];
    const float* Wv = (const float*)d_in[3];
    float* out = (float*)d_out;

    const size_t n = (size_t)NB * NS * NH;            // 1,048,576 elements
    unsigned short* qb_ = (unsigned short*)d_ws;      // 2 MB
    unsigned short* kb_ = qb_ + n;                    // 2 MB
    unsigned short* vT  = kb_ + n;                    // 2 MB (layout [b][h][s])
    unsigned short* wT  = vT + n;                     // 384 KB (layout [192][1024])
    float* pO  = (float*)(wT + 192 * 1024);           // 1152 x 4096 f32 = 18.9 MB
    float* pm_ = pO + (size_t)1152 * 4096;            // 1152 x 64 f32
    float* pl_ = pm_ + 1152 * 64;                     // 1152 x 64 f32

    wconv<<<dim3(192), dim3(256), 0, stream>>>(Wq, Wk, Wv, wT);
    qkv_proj<<<dim3(512), dim3(256), 0, stream>>>(x, wT, qb_, kb_, vT);
    attn_part<<<dim3(2048), dim3(256), 0, stream>>>(qb_, kb_, vT, pO, pm_, pl_);
    attn_merge<<<dim3(256), dim3(256), 0, stream>>>(pO, pm_, pl_, out);
}